// Round 2
// baseline (1032.153 us; speedup 1.0000x reference)
//
#include <hip/hip_runtime.h>
#include <hip/hip_bf16.h>

// FixedRadiusNNGraph: outputs (adj[B,N,N], dists[B,N,N], pts[B,N,3], feats[B,N,F])
// concatenated flat as float32. B=2, N=8192, F=64 -> 1.078 GB output, pure
// HBM-write-bound (floor ~171 us at 6.3 TB/s).
//
// Layout per block: 256 threads, 4 rows (i) x 1024 cols (j). Each thread owns
// 4 consecutive j points held in registers (loaded once, reused for 4 rows),
// writes float4 dists + float4 adj per row. i-points are block-uniform ->
// scalar loads. Inputs are tiny (192 KB points) and L2-resident.

typedef float v4f __attribute__((ext_vector_type(4)));  // clang vector: valid
                                                        // for nontemporal builtins

__global__ __launch_bounds__(256) void frnn_dist_adj_kernel(
    const float* __restrict__ pts,   // [B*N, 3]
    float* __restrict__ adj_out,     // [B*N, N] (row gi = b*N + i)
    float* __restrict__ dist_out,    // [B*N, N]
    int N, float r2)
{
    const int t   = threadIdx.x;
    const int j0  = blockIdx.x * 1024;       // j tile start (within cloud)
    const int gi0 = blockIdx.y * 4;          // first global row (b*N + i)
    const int b   = gi0 / N;                 // batch index (4 rows never straddle)

    // ---- load this thread's 4 j-points (12 contiguous floats, 16B aligned) ----
    const int jbase = b * N + j0 + 4 * t;    // global point index of first j
    const v4f* p4 = (const v4f*)(pts + (size_t)jbase * 3);
    const v4f q0 = p4[0];
    const v4f q1 = p4[1];
    const v4f q2 = p4[2];
    // points memory: x0 y0 z0 x1 | y1 z1 x2 y2 | z2 x3 y3 z3
    float xj[4] = {q0.x, q0.w, q1.z, q2.y};
    float yj[4] = {q0.y, q1.x, q1.w, q2.z};
    float zj[4] = {q0.z, q1.y, q2.x, q2.w};
    float sj[4];
#pragma unroll
    for (int k = 0; k < 4; ++k)
        sj[k] = fmaf(xj[k], xj[k], fmaf(yj[k], yj[k], zj[k] * zj[k]));

#pragma unroll
    for (int r = 0; r < 4; ++r) {
        const int gi = gi0 + r;              // block-uniform -> s_load path
        const float xi = pts[(size_t)gi * 3 + 0];
        const float yi = pts[(size_t)gi * 3 + 1];
        const float zi = pts[(size_t)gi * 3 + 2];
        const float si = fmaf(xi, xi, fmaf(yi, yi, zi * zi));

        float d[4];
#pragma unroll
        for (int k = 0; k < 4; ++k) {
            const float dot = fmaf(xi, xj[k], fmaf(yi, yj[k], zi * zj[k]));
            d[k] = fmaf(-2.0f, dot, si + sj[k]);   // exact 0 on the diagonal
        }
        v4f dv = {d[0], d[1], d[2], d[3]};
        v4f av = {d[0] <= r2 ? 1.0f : 0.0f,
                  d[1] <= r2 ? 1.0f : 0.0f,
                  d[2] <= r2 ? 1.0f : 0.0f,
                  d[3] <= r2 ? 1.0f : 0.0f};
        const size_t off = (size_t)gi * N + (size_t)(j0 + 4 * t);
        __builtin_nontemporal_store(dv, (v4f*)(dist_out + off));
        __builtin_nontemporal_store(av, (v4f*)(adj_out  + off));
    }
}

extern "C" void kernel_launch(void* const* d_in, const int* in_sizes, int n_in,
                              void* d_out, int out_size, void* d_ws, size_t ws_size,
                              hipStream_t stream) {
    const float* pts   = (const float*)d_in[0];   // [B*N, 3]
    const float* feats = (const float*)d_in[1];   // [B*N, F]
    // d_in[2] = batch_len (uniform segments; offsets are b*N by construction)

    const int B  = in_sizes[2] - 1;               // batch_len has B+1 entries
    const int BN = in_sizes[0] / 3;               // total points
    const int N  = BN / B;                        // points per cloud
    const float r2 = 0.3f * 0.3f;

    float* adj_out  = (float*)d_out;                          // B*N*N
    float* dist_out = adj_out + (size_t)B * N * N;            // B*N*N
    float* pts_out  = dist_out + (size_t)B * N * N;           // B*N*3
    float* feat_out = pts_out + (size_t)in_sizes[0];          // B*N*F

    // pts / feats outputs are exact copies of the inputs (reshape only).
    (void)hipMemcpyAsync(pts_out,  pts,   (size_t)in_sizes[0] * sizeof(float),
                         hipMemcpyDeviceToDevice, stream);
    (void)hipMemcpyAsync(feat_out, feats, (size_t)in_sizes[1] * sizeof(float),
                         hipMemcpyDeviceToDevice, stream);

    // dists + adj: grid (N/1024 j-tiles, BN/4 row groups), 256 threads/block.
    dim3 grid(N / 1024, BN / 4);
    frnn_dist_adj_kernel<<<grid, 256, 0, stream>>>(pts, adj_out, dist_out, N, r2);
}